// Round 1
// baseline (241.473 us; speedup 1.0000x reference)
//
#include <hip/hip_runtime.h>
#include <math.h>

#define N_BINS 256
#define TAU 0.01f
#define EPS 1e-10f
#define WIN 16            // +/- window; weight at 16 bins = exp(-19.7) ~ 3e-9 (negligible)
#define HW (512*512)

// -------- Pass 1: per-batch soft histogram --------
// grid: (HW/4/256, B), block: 256. Each thread handles 4 pixels (float4).
__global__ void hist_kernel(const float* __restrict__ x, float* __restrict__ hist) {
    __shared__ float lhist[N_BINS];
    const int b   = blockIdx.y;
    const int tid = threadIdx.x;
    lhist[tid] = 0.0f;                    // 256 threads == 256 bins
    __syncthreads();

    const float4* xb = (const float4*)(x + (size_t)b * HW);
    const int idx = blockIdx.x * blockDim.x + tid;
    const float4 v = xb[idx];
    const float vals[4] = {v.x, v.y, v.z, v.w};
    const float inv2tau2 = 1.0f / (2.0f * TAU * TAU);

#pragma unroll
    for (int k = 0; k < 4; ++k) {
        const float xv = vals[k];
        const int j0  = __float2int_rn(xv * 255.0f);
        const int jlo = max(0, j0 - WIN);
        const int jhi = min(N_BINS - 1, j0 + WIN);
        for (int j = jlo; j <= jhi; ++j) {
            const float d = xv - (float)j * (1.0f / 255.0f);
            const float w = __expf(-d * d * inv2tau2);
            atomicAdd(&lhist[j], w);
        }
    }
    __syncthreads();
    atomicAdd(&hist[b * N_BINS + tid], lhist[tid]);
}

// -------- Pass 2: normalize + cumsum + cdf normalization --------
// grid: (B), block: 256. Hillis-Steele inclusive scan in LDS.
__global__ void cdf_kernel(const float* __restrict__ hist, float* __restrict__ cdfn) {
    __shared__ float sh[N_BINS];
    const int b   = blockIdx.x;
    const int tid = threadIdx.x;
    float val = hist[b * N_BINS + tid];
    sh[tid] = val;
    __syncthreads();

    for (int off = 1; off < N_BINS; off <<= 1) {
        const float t = (tid >= off) ? sh[tid - off] : 0.0f;
        __syncthreads();
        val += t;
        sh[tid] = val;
        __syncthreads();
    }
    const float total = sh[N_BINS - 1];
    const float inv   = 1.0f / (total + EPS);
    const float cdf   = val * inv;
    const float cdf0  = sh[0] * inv;
    cdfn[b * N_BINS + tid] = (cdf - cdf0) / (1.0f - cdf0 + EPS);
}

// -------- Pass 3: per-pixel equalization --------
// out_p = (sum_j w_j * cdfn_j) / (sum_j w_j + EPS), windowed.
__global__ void equalize_kernel(const float* __restrict__ x,
                                const float* __restrict__ cdfn,
                                float* __restrict__ out) {
    __shared__ float sc[N_BINS];
    const int b   = blockIdx.y;
    const int tid = threadIdx.x;
    sc[tid] = cdfn[b * N_BINS + tid];
    __syncthreads();

    const float4* xb = (const float4*)(x + (size_t)b * HW);
    float4*       ob = (float4*)(out + (size_t)b * HW);
    const int idx = blockIdx.x * blockDim.x + tid;
    const float4 v = xb[idx];
    const float vals[4] = {v.x, v.y, v.z, v.w};
    float res[4];
    const float inv2tau2 = 1.0f / (2.0f * TAU * TAU);

#pragma unroll
    for (int k = 0; k < 4; ++k) {
        const float xv = vals[k];
        const int j0  = __float2int_rn(xv * 255.0f);
        const int jlo = max(0, j0 - WIN);
        const int jhi = min(N_BINS - 1, j0 + WIN);
        float sw = 0.0f, swc = 0.0f;
        for (int j = jlo; j <= jhi; ++j) {
            const float d = xv - (float)j * (1.0f / 255.0f);
            const float w = __expf(-d * d * inv2tau2);
            sw  += w;
            swc += w * sc[j];
        }
        res[k] = swc / (sw + EPS);
    }
    ob[idx] = make_float4(res[0], res[1], res[2], res[3]);
}

extern "C" void kernel_launch(void* const* d_in, const int* in_sizes, int n_in,
                              void* d_out, int out_size, void* d_ws, size_t ws_size,
                              hipStream_t stream) {
    const float* x = (const float*)d_in[0];
    float* out     = (float*)d_out;
    const int B    = in_sizes[0] / HW;   // = 4

    float* hist = (float*)d_ws;          // B*256 floats
    float* cdfn = hist + B * N_BINS;     // B*256 floats

    hipMemsetAsync(hist, 0, (size_t)B * N_BINS * sizeof(float), stream);

    dim3 grid(HW / 4 / 256, B);
    hist_kernel<<<grid, 256, 0, stream>>>(x, hist);
    cdf_kernel<<<B, 256, 0, stream>>>(hist, cdfn);
    equalize_kernel<<<grid, 256, 0, stream>>>(x, cdfn, out);
}

// Round 2
// 87.840 us; speedup vs baseline: 2.7490x; 2.7490x over previous
//
#include <hip/hip_runtime.h>
#include <math.h>

#define N_BINS 256
#define TAU 0.01f
#define EPS 1e-10f
#define HW (512*512)
#define Q 4081            // quant levels; Q-1 = 4080 = 16*255 so t_q - b_j = (q-16j)/4080
#define QSTRIDE 4096
#define MWIN 270          // |q-16j| <= 270 -> w = exp(-21.9) ~ 3e-10, negligible beyond
#define WTAB (2*MWIN+1)   // 541

__device__ __forceinline__ int swz(int q) { return q + (q >> 4); }  // pad every 16 words

// -------- Pass 1: per-batch fine hard histogram (1 LDS atomic / pixel) --------
// grid: (16, B), block: 256. Each thread: 16 float4 = 64 pixels.
__global__ void fine_hist_kernel(const float* __restrict__ x, unsigned int* __restrict__ c) {
    __shared__ unsigned int lh[Q];
    const int b   = blockIdx.y;
    const int bx  = blockIdx.x;
    const int tid = threadIdx.x;
    for (int i = tid; i < Q; i += 256) lh[i] = 0u;
    __syncthreads();

    const float4* xb = (const float4*)(x + (size_t)b * HW);
    const int base = bx * (HW / 4 / 16);       // 4096 float4 per block
#pragma unroll
    for (int i = 0; i < 16; ++i) {
        const float4 v = xb[base + i * 256 + tid];
        int q0 = __float2int_rn(v.x * 4080.f);
        int q1 = __float2int_rn(v.y * 4080.f);
        int q2 = __float2int_rn(v.z * 4080.f);
        int q3 = __float2int_rn(v.w * 4080.f);
        q0 = min(max(q0, 0), Q - 1); q1 = min(max(q1, 0), Q - 1);
        q2 = min(max(q2, 0), Q - 1); q3 = min(max(q3, 0), Q - 1);
        atomicAdd(&lh[q0], 1u); atomicAdd(&lh[q1], 1u);
        atomicAdd(&lh[q2], 1u); atomicAdd(&lh[q3], 1u);
    }
    __syncthreads();
    // merge to global, rotated start so concurrent blocks hit different addresses
    for (int k = 0; k < 16; ++k) {
        const int i = tid + (((k + bx) & 15) << 8);
        if (i < Q) {
            const unsigned int cnt = lh[i];
            if (cnt) atomicAdd(&c[b * QSTRIDE + i], cnt);
        }
    }
}

// -------- Pass 2: conv -> hist -> scan -> cdfn -> output LUT (per batch, 1 block) --------
__global__ __launch_bounds__(1024) void cdf_lut_kernel(const unsigned int* __restrict__ c,
                                                       float* __restrict__ T) {
    __shared__ float cf[Q + (Q >> 4) + 2];   // swizzled fine hist (~4336 floats)
    __shared__ float wt[WTAB];
    __shared__ float ph[1024];
    __shared__ float hs[N_BINS];
    __shared__ float cdfn_s[N_BINS];
    const int b   = blockIdx.x;
    const int tid = threadIdx.x;

    for (int q = tid; q < Q; q += 1024) cf[swz(q)] = (float)c[b * QSTRIDE + q];
    if (tid < WTAB) {
        const float d = (float)(tid - MWIN) * (1.0f / 4080.f);
        wt[tid] = __expf(-d * d * (1.0f / (2.0f * TAU * TAU)));
    }
    __syncthreads();

    // soft hist[j] = sum_m wt[m] * c[16j - 270 + m]; 4 partial-threads per bin
    {
        const int j = tid >> 2, s = tid & 3;
        const int base = 16 * j - MWIN;
        float acc = 0.f;
        for (int m = s; m < WTAB; m += 4) {
            const int q = base + m;
            if (q >= 0 && q < Q) acc += wt[m] * cf[swz(q)];
        }
        ph[tid] = acc;
    }
    __syncthreads();
    float val = 0.f;
    if (tid < N_BINS) {
        val = ph[4 * tid] + ph[4 * tid + 1] + ph[4 * tid + 2] + ph[4 * tid + 3];
        hs[tid] = val;
    }
    __syncthreads();
    // Hillis-Steele inclusive scan over 256 bins (all threads hit barriers)
    for (int off = 1; off < N_BINS; off <<= 1) {
        float t = 0.f;
        if (tid < N_BINS && tid >= off) t = hs[tid - off];
        __syncthreads();
        if (tid < N_BINS) { val += t; hs[tid] = val; }
        __syncthreads();
    }
    if (tid < N_BINS) {
        const float total = hs[N_BINS - 1];
        const float inv   = 1.0f / (total + EPS);
        const float cdf   = val * inv;
        const float cdf0  = hs[0] * inv;
        cdfn_s[tid] = (cdf - cdf0) / (1.0f - cdf0 + EPS);
    }
    __syncthreads();
    // output LUT: T[q] = (sum_j wt[q-16j+270]*cdfn[j]) / (sum_j wt + EPS)
    for (int q = tid; q < Q; q += 1024) {
        int jlo = (q - MWIN + 15) >> 4; if (jlo < 0)   jlo = 0;
        int jhi = (q + MWIN) >> 4;      if (jhi > 255) jhi = 255;
        float sw = 0.f, swc = 0.f;
        for (int jj = jlo; jj <= jhi; ++jj) {
            const float w = wt[q - 16 * jj + MWIN];
            sw  += w;
            swc += w * cdfn_s[jj];
        }
        T[b * QSTRIDE + q] = swc / (sw + EPS);
    }
}

// -------- Pass 3: per-pixel lerp through the LUT --------
// grid: (256, B), block: 256.
__global__ void equalize_lut_kernel(const float* __restrict__ x,
                                    const float* __restrict__ T,
                                    float* __restrict__ out) {
    __shared__ float Ts[QSTRIDE];
    const int b   = blockIdx.y;
    const int tid = threadIdx.x;
    const float4* Tg = (const float4*)(T + (size_t)b * QSTRIDE);
    float4* Ts4 = (float4*)Ts;
#pragma unroll
    for (int i = 0; i < 4; ++i) Ts4[i * 256 + tid] = Tg[i * 256 + tid];
    __syncthreads();

    const float4* xb = (const float4*)(x + (size_t)b * HW);
    float4*       ob = (float4*)(out + (size_t)b * HW);
    const int idx = blockIdx.x * 256 + tid;
    const float4 v = xb[idx];
    const float vals[4] = {v.x, v.y, v.z, v.w};
    float res[4];
#pragma unroll
    for (int k = 0; k < 4; ++k) {
        const float u = vals[k] * 4080.f;
        int q = (int)u;
        q = min(max(q, 0), Q - 2);
        const float frac = u - (float)q;
        const float t0 = Ts[q], t1 = Ts[q + 1];
        res[k] = fmaf(frac, t1 - t0, t0);
    }
    ob[idx] = make_float4(res[0], res[1], res[2], res[3]);
}

extern "C" void kernel_launch(void* const* d_in, const int* in_sizes, int n_in,
                              void* d_out, int out_size, void* d_ws, size_t ws_size,
                              hipStream_t stream) {
    const float* x = (const float*)d_in[0];
    float* out     = (float*)d_out;
    const int B    = in_sizes[0] / HW;   // = 4

    unsigned int* c = (unsigned int*)d_ws;                 // B*4096 uint
    float* T        = (float*)d_ws + (size_t)B * QSTRIDE;  // B*4096 float

    hipMemsetAsync(c, 0, (size_t)B * QSTRIDE * sizeof(unsigned int), stream);

    fine_hist_kernel<<<dim3(16, B), 256, 0, stream>>>(x, c);
    cdf_lut_kernel<<<B, 1024, 0, stream>>>(c, T);
    equalize_lut_kernel<<<dim3(HW / 4 / 256, B), 256, 0, stream>>>(x, T, out);
}

// Round 3
// 75.948 us; speedup vs baseline: 3.1795x; 1.1566x over previous
//
#include <hip/hip_runtime.h>
#include <math.h>

#define N_BINS 256
#define TAU 0.01f
#define EPS 1e-10f
#define HW (512*512)
#define Q 4081            // quant levels; Q-1 = 4080 = 16*255 so t_q - b_j = (q-16j)/4080
#define QSTRIDE 4096
#define MWIN 208          // |q-16j| <= 208 -> dropped weight exp(-13) ~ 2e-6 (negligible)
#define WTAB (2*MWIN+1)   // 417
#define WPAD 420          // wt padded to multiple of 4 (zeros)
#define CFPAD 4512        // >= 16*255+WPAD-1 = 4499, multiple of 4

// -------- Pass 1: per-batch fine hard histogram --------
// grid: (64, B), block: 256. Each thread: 4 float4 = 16 pixels.
__global__ void fine_hist_kernel(const float* __restrict__ x, unsigned int* __restrict__ c) {
    __shared__ unsigned int lh[Q];
    const int b   = blockIdx.y;
    const int bx  = blockIdx.x;
    const int tid = threadIdx.x;
    for (int i = tid; i < Q; i += 256) lh[i] = 0u;
    __syncthreads();

    const float4* xb = (const float4*)(x + (size_t)b * HW);
    const int base = bx * 1024;                // 1024 float4 per block
#pragma unroll
    for (int i = 0; i < 4; ++i) {
        const float4 v = xb[base + i * 256 + tid];
        int q0 = __float2int_rn(v.x * 4080.f);
        int q1 = __float2int_rn(v.y * 4080.f);
        int q2 = __float2int_rn(v.z * 4080.f);
        int q3 = __float2int_rn(v.w * 4080.f);
        q0 = min(max(q0, 0), Q - 1); q1 = min(max(q1, 0), Q - 1);
        q2 = min(max(q2, 0), Q - 1); q3 = min(max(q3, 0), Q - 1);
        atomicAdd(&lh[q0], 1u); atomicAdd(&lh[q1], 1u);
        atomicAdd(&lh[q2], 1u); atomicAdd(&lh[q3], 1u);
    }
    __syncthreads();
    // merge to global, rotated start so concurrent blocks hit different addresses
    for (int k = 0; k < 16; ++k) {
        const int i = tid + (((k + bx) & 15) << 8);
        if (i < Q) {
            const unsigned int cnt = lh[i];
            if (cnt) atomicAdd(&c[b * QSTRIDE + i], cnt);
        }
    }
}

// -------- Pass 2: conv -> hist -> scan -> cdfn -> float2 LUT (1 block / batch) --------
__global__ __launch_bounds__(1024) void cdf_lut_kernel(const unsigned int* __restrict__ c,
                                                       float2* __restrict__ T2) {
    __shared__ __align__(16) float cf[CFPAD];  // cf[16j+m] = count[16j+m-MWIN], zero outside
    __shared__ __align__(16) float wt[WPAD];
    __shared__ float ph[1024];
    __shared__ float hs[N_BINS];
    __shared__ float cdfn_s[N_BINS];
    __shared__ float S16[16];
    __shared__ float Tl[QSTRIDE];
    const int b   = blockIdx.x;
    const int tid = threadIdx.x;

    for (int i = tid; i < CFPAD; i += 1024) {
        const int q = i - MWIN;
        cf[i] = (q >= 0 && q < Q) ? (float)c[b * QSTRIDE + q] : 0.f;
    }
    for (int i = tid; i < WPAD; i += 1024) {
        const float d = (float)(i - MWIN) * (1.0f / 4080.f);
        wt[i] = (i < WTAB) ? __expf(-d * d * (1.0f / (2.0f * TAU * TAU))) : 0.f;
    }
    __syncthreads();

    // soft hist[j] = sum_m wt[m] * cf[16j+m], vectorized: 105 float4 MACs split 4 ways
    {
        const int j = tid >> 2, s = tid & 3;
        const float4* cf4 = (const float4*)cf;
        const float4* wt4 = (const float4*)wt;
        const int klo = s * 27;
        const int khi = min(WPAD / 4, klo + 27);
        float acc = 0.f;
        for (int k = klo; k < khi; ++k) {
            const float4 a = cf4[4 * j + k];
            const float4 w = wt4[k];
            acc += a.x * w.x + a.y * w.y + a.z * w.z + a.w * w.w;
        }
        ph[tid] = acc;
    }
    if (tid < 16) {  // per-residue weight sums for interior denominators
        float s = 0.f;
        for (int m = tid; m < WTAB; m += 16) s += wt[m];
        S16[tid] = s;
    }
    __syncthreads();
    float val = 0.f;
    if (tid < N_BINS) {
        val = ph[4 * tid] + ph[4 * tid + 1] + ph[4 * tid + 2] + ph[4 * tid + 3];
        hs[tid] = val;
    }
    __syncthreads();
    // Hillis-Steele inclusive scan over 256 bins (all threads hit barriers)
    for (int off = 1; off < N_BINS; off <<= 1) {
        float t = 0.f;
        if (tid < N_BINS && tid >= off) t = hs[tid - off];
        __syncthreads();
        if (tid < N_BINS) { val += t; hs[tid] = val; }
        __syncthreads();
    }
    if (tid < N_BINS) {
        const float total = hs[N_BINS - 1];
        const float inv   = 1.0f / (total + EPS);
        const float cdf   = val * inv;
        const float cdf0  = hs[0] * inv;
        cdfn_s[tid] = (cdf - cdf0) / (1.0f - cdf0 + EPS);
    }
    __syncthreads();
    // output LUT: T[q] = (sum_j wt[q-16j+MWIN]*cdfn[j]) / (sum_j wt + EPS)
    for (int qi = tid; qi < QSTRIDE; qi += 1024) {
        float Tv = 0.f;
        if (qi < Q) {
            const int jlo = max(0, (qi - MWIN + 15) >> 4);
            const int jhi = min(N_BINS - 1, (qi + MWIN) >> 4);
            float swc = 0.f;
            for (int j = jlo; j <= jhi; ++j)
                swc += wt[qi - 16 * j + MWIN] * cdfn_s[j];
            float sw;
            if (qi >= MWIN && qi <= 16 * N_BINS - MWIN - 1) {
                sw = S16[(qi + MWIN) & 15];
            } else {
                sw = 0.f;
                for (int j = jlo; j <= jhi; ++j) sw += wt[qi - 16 * j + MWIN];
            }
            Tv = swc / (sw + EPS);
        }
        Tl[qi] = Tv;
    }
    __syncthreads();
    for (int qi = tid; qi < QSTRIDE; qi += 1024) {
        const float t0 = Tl[qi];
        const float t1 = Tl[min(qi + 1, Q - 1)];
        T2[b * QSTRIDE + qi] = make_float2(t0, t1);
    }
}

// -------- Pass 3: per-pixel lerp, one b64 LDS read / pixel --------
// grid: (256, B), block: 256.
__global__ void equalize_lut_kernel(const float* __restrict__ x,
                                    const float2* __restrict__ T2,
                                    float* __restrict__ out) {
    __shared__ __align__(16) float2 Ts[QSTRIDE];   // 32 KB
    const int b   = blockIdx.y;
    const int tid = threadIdx.x;
    const float4* Tg  = (const float4*)(T2 + (size_t)b * QSTRIDE);
    float4*       Ts4 = (float4*)Ts;
#pragma unroll
    for (int i = 0; i < 8; ++i) Ts4[i * 256 + tid] = Tg[i * 256 + tid];
    __syncthreads();

    const float4* xb = (const float4*)(x + (size_t)b * HW);
    float4*       ob = (float4*)(out + (size_t)b * HW);
    const int idx = blockIdx.x * 256 + tid;
    const float4 v = xb[idx];
    const float vals[4] = {v.x, v.y, v.z, v.w};
    float res[4];
#pragma unroll
    for (int k = 0; k < 4; ++k) {
        const float u = vals[k] * 4080.f;
        int q = (int)u;
        q = min(max(q, 0), Q - 2);
        const float frac = u - (float)q;
        const float2 t = Ts[q];
        res[k] = fmaf(frac, t.y - t.x, t.x);
    }
    ob[idx] = make_float4(res[0], res[1], res[2], res[3]);
}

extern "C" void kernel_launch(void* const* d_in, const int* in_sizes, int n_in,
                              void* d_out, int out_size, void* d_ws, size_t ws_size,
                              hipStream_t stream) {
    const float* x = (const float*)d_in[0];
    float* out     = (float*)d_out;
    const int B    = in_sizes[0] / HW;   // = 4

    unsigned int* c = (unsigned int*)d_ws;                               // B*4096 uint
    float2* T2      = (float2*)((char*)d_ws + (size_t)B * QSTRIDE * 4);  // B*4096 float2

    hipMemsetAsync(c, 0, (size_t)B * QSTRIDE * sizeof(unsigned int), stream);

    fine_hist_kernel<<<dim3(64, B), 256, 0, stream>>>(x, c);
    cdf_lut_kernel<<<B, 1024, 0, stream>>>(c, T2);
    equalize_lut_kernel<<<dim3(HW / 4 / 256, B), 256, 0, stream>>>(x, T2, out);
}